// Round 10
// baseline (310.134 us; speedup 1.0000x reference)
//
#include <hip/hip_runtime.h>
#include <math.h>

#define B_    64
#define S_    512
#define EMB_  768
#define HID_  512
#define IMG_  2048
#define ATT_  512
#define K_    6
#define HL_   20
#define MS_   (B_ * S_)            // 32768

typedef __attribute__((ext_vector_type(8))) short bf16x8;
typedef __attribute__((ext_vector_type(4))) float f32x4;

__device__ __forceinline__ unsigned short f2b(float f) {
    unsigned int u = __float_as_uint(f);
    u += 0x7fffu + ((u >> 16) & 1u);          // RNE
    return (unsigned short)(u >> 16);
}
__device__ __forceinline__ unsigned int pk_bf16(float lo, float hi) {
    unsigned int r;
    asm volatile("v_cvt_pk_bf16_f32 %0, %1, %2" : "=v"(r) : "v"(lo), "v"(hi));
    return r;
}
__device__ __forceinline__ bf16x8 cvt8(const float4& x, const float4& y) {
    union { unsigned int u[4]; bf16x8 v; } r;
    r.u[0] = pk_bf16(x.x, x.y);
    r.u[1] = pk_bf16(x.z, x.w);
    r.u[2] = pk_bf16(y.x, y.y);
    r.u[3] = pk_bf16(y.z, y.w);
    return r.v;
}
__device__ __forceinline__ int swz4(int r) { return (r ^ (r >> 2)) & 3; }
__device__ __forceinline__ int swz8(int r) { return (r ^ (r >> 3)) & 7; }

#define GLD_LDS16(gp, lp)                                                        \
    __builtin_amdgcn_global_load_lds(                                            \
        (const __attribute__((address_space(1))) void*)(gp),                     \
        (__attribute__((address_space(3))) void*)(lp), 16, 0, 0)

// ---------------------------------------------------------------------------
// prep: z=0..2 -> transpose+cvt of W_e2h / W_mm[:H] / W_a1 ; z=3 -> mask probe
__global__ __launch_bounds__(256)
void prep(const float* __restrict__ W_e2h, const float* __restrict__ W_mm,
          const float* __restrict__ W_a1,
          unsigned short* __restrict__ WtE2H, unsigned short* __restrict__ WtMM,
          unsigned short* __restrict__ WtA1,
          const unsigned char* __restrict__ masks, int* __restrict__ flag) {
    const int z = blockIdx.z;
    if (z == 3) {
        if (blockIdx.x != 0 || blockIdx.y != 0) return;
        __shared__ int found;
        if (threadIdx.x == 0) found = 0;
        __syncthreads();
        for (int i = threadIdx.x; i < 8192; i += 256)
            if ((i & 3) != 0 && masks[i] != 0) found = 1;
        __syncthreads();
        if (threadIdx.x == 0) *flag = found;
        return;
    }
    const float* W;
    unsigned short* Wt;
    int Kd;
    if (z == 0)      { W = W_e2h; Wt = WtE2H; Kd = EMB_; }
    else if (z == 1) { W = W_mm;  Wt = WtMM;  Kd = HID_; }
    else             { W = W_a1;  Wt = WtA1;  Kd = HID_; }
    if ((int)blockIdx.x * 32 >= Kd) return;

    __shared__ float tile[32][33];
    int k0 = blockIdx.x * 32, n0 = blockIdx.y * 32;
    int tx = threadIdx.x & 31, ty = threadIdx.x >> 5;   // 32 x 8
    #pragma unroll
    for (int i = 0; i < 4; ++i)
        tile[ty + i * 8][tx] = W[(size_t)(k0 + ty + i * 8) * HID_ + n0 + tx];
    __syncthreads();
    #pragma unroll
    for (int i = 0; i < 4; ++i)
        Wt[(size_t)(n0 + ty + i * 8) * Kd + k0 + tx] = f2b(tile[tx][ty + i * 8]);
}

// ---------------------------------------------------------------------------
// XCD-chunked bijective block swizzle helper (nwg % 8 == 0). 64-wide tiles.
__device__ __forceinline__ void tile_coords64(int N, int& bm, int& bn) {
    const int nwg = gridDim.x;
    const int cpx = nwg >> 3;
    const int lid = ((int)blockIdx.x & 7) * cpx + ((int)blockIdx.x >> 3);
    const int ntl = N >> 6;
    bn = (lid % ntl) << 6;
    bm = (lid / ntl) << 6;
}

// ---------------------------------------------------------------------------
// Barrier-free 1-wave MFMA GEMM: 64 threads/block, 64x64 tile, BK=32, dbuf
// LDS, stage-early prefetch with a single wave-local counted s_waitcnt per
// iteration (no s_barrier, no sched_barrier: compiler schedules freely; TLP
// from many independent wave-blocks hides latency).
// AF32: A is fp32, staged to LDS as fp32 via gld_lds, converted at frag read.
// SCORE: tanh+dot-W_a2 epilogue, slot = bn/64 (8 slots over N=512).
template<bool AF32, int ACT, bool SCORE>
__global__ __launch_bounds__(64)
void gemm_wave(const void* __restrict__ Av, const unsigned short* __restrict__ Bt,
               const float* __restrict__ bias, const float* __restrict__ row_add,
               int row_div, unsigned short* __restrict__ Co,
               const float* __restrict__ W_a2, float* __restrict__ scores8,
               int M, int N, int Kd) {
    __shared__ unsigned short Bls[2][64 * 32];                    // 8 KB
    __shared__ float          AlsF[2][AF32 ? 64 * 32 : 16];       // 16 KB | -
    __shared__ unsigned short AlsB[2][AF32 ? 16 : 64 * 32];       // -     | 8 KB

    const int lane = threadIdx.x;
    int bm, bn; tile_coords64(N, bm, bn);
    const int fr = lane & 15, hi = lane >> 4;

    const unsigned short* Ab = (const unsigned short*)Av;
    const float* Af = (const float*)Av;

    f32x4 acc[4][4] = {};

    auto stageB = [&](int t, int buf) {           // 4 gld_lds
        #pragma unroll
        for (int c = 0; c < 4; ++c) {
            int g = c * 64 + lane;
            int r = g >> 2, d = g & 3;
            GLD_LDS16(Bt + (size_t)(bn + r) * Kd + t * 32 + (d ^ swz4(r)) * 8,
                      &Bls[buf][g * 8]);
        }
    };
    auto stageA = [&](int t, int buf) {           // 8 (fp32) or 4 (bf16)
        if constexpr (AF32) {
            #pragma unroll
            for (int c = 0; c < 8; ++c) {
                int g = c * 64 + lane;
                int r = g >> 3, d = g & 7;
                GLD_LDS16(Af + (size_t)(bm + r) * Kd + t * 32 + (d ^ swz8(r)) * 4,
                          &AlsF[buf][g * 4]);
            }
        } else {
            #pragma unroll
            for (int c = 0; c < 4; ++c) {
                int g = c * 64 + lane;
                int r = g >> 2, d = g & 3;
                GLD_LDS16(Ab + (size_t)(bm + r) * Kd + t * 32 + (d ^ swz4(r)) * 8,
                          &AlsB[buf][g * 8]);
            }
        }
    };
    auto compute = [&](int buf) {
        bf16x8 af[4], bv[4];
        #pragma unroll
        for (int m = 0; m < 4; ++m) {
            int r = m * 16 + fr;
            if constexpr (AF32) {
                float4 x = *(const float4*)&AlsF[buf][r * 32 + ((2 * hi) ^ swz8(r)) * 4];
                float4 y = *(const float4*)&AlsF[buf][r * 32 + ((2 * hi + 1) ^ swz8(r)) * 4];
                af[m] = cvt8(x, y);
            } else {
                af[m] = *(const bf16x8*)&AlsB[buf][r * 32 + (hi ^ swz4(r)) * 8];
            }
        }
        #pragma unroll
        for (int n = 0; n < 4; ++n) {
            int r = n * 16 + fr;
            bv[n] = *(const bf16x8*)&Bls[buf][r * 32 + (hi ^ swz4(r)) * 8];
        }
        __builtin_amdgcn_s_setprio(1);
        #pragma unroll
        for (int m = 0; m < 4; ++m)
            #pragma unroll
            for (int n = 0; n < 4; ++n)
                acc[m][n] = __builtin_amdgcn_mfma_f32_16x16x32_bf16(af[m], bv[n], acc[m][n], 0, 0, 0);
        __builtin_amdgcn_s_setprio(0);
    };

    const int nt = Kd >> 5;

    stageA(0, 0);
    stageB(0, 0);
    for (int t = 0; t < nt; ++t) {
        const int buf = t & 1;
        const bool pf = (t + 1 < nt);
        if (pf) {
            stageA(t + 1, buf ^ 1);
            stageB(t + 1, buf ^ 1);
        }
        // wave-local counted wait: tile t's loads done, tile t+1's in flight
        if (pf) {
            if constexpr (AF32) asm volatile("s_waitcnt vmcnt(12)" ::: "memory");
            else                asm volatile("s_waitcnt vmcnt(8)"  ::: "memory");
        } else {
            asm volatile("s_waitcnt vmcnt(0)" ::: "memory");
        }
        compute(buf);
    }

    // --- epilogue ---------------------------------------------------------
    if (SCORE) {
        float ba[4], wa[4];
        #pragma unroll
        for (int n = 0; n < 4; ++n) {
            int col = bn + n * 16 + fr;
            ba[n] = bias[col];
            wa[n] = W_a2[col];
        }
        const int slot = bn >> 6;
        #pragma unroll
        for (int m = 0; m < 4; ++m) {
            #pragma unroll
            for (int r = 0; r < 4; ++r) {
                float p = 0.f;
                #pragma unroll
                for (int n = 0; n < 4; ++n)
                    p += tanhf(acc[m][n][r] + ba[n]) * wa[n];
                p += __shfl_xor(p, 1, 64);
                p += __shfl_xor(p, 2, 64);
                p += __shfl_xor(p, 4, 64);
                p += __shfl_xor(p, 8, 64);
                if (fr == 0)
                    scores8[(size_t)slot * M + bm + m * 16 + hi * 4 + r] = p;
            }
        }
    } else {
        #pragma unroll
        for (int m = 0; m < 4; ++m) {
            #pragma unroll
            for (int n = 0; n < 4; ++n) {
                int col = bn + n * 16 + fr;
                float badd = bias ? bias[col] : 0.f;
                #pragma unroll
                for (int r = 0; r < 4; ++r) {
                    int row = bm + m * 16 + hi * 4 + r;
                    float x = acc[m][n][r] + badd;
                    if (row_add) x += row_add[(size_t)(row / row_div) * N + col];
                    if (ACT == 1) x = fmaxf(x, 0.f);
                    Co[(size_t)row * N + col] = f2b(x);
                }
            }
        }
    }
}

// ---------------------------------------------------------------------------
// split-K partial fp32 GEMM: P[z, m, n] = A[m, kz..kz+kps) @ W[.., n]
__global__ __launch_bounds__(256)
void gemm_splitk(const float* __restrict__ A, const float* __restrict__ W,
                 float* __restrict__ P, int M, int N, int Kd, int kps) {
    __shared__ float As[16][68];
    __shared__ float Ws[16][64];
    const int tid = threadIdx.x;
    const int bm = blockIdx.y * 64, bn = blockIdx.x * 64;
    const int ks = blockIdx.z;
    const int tx = tid & 15, ty = tid >> 4;
    const int arow = tid >> 2, akq = tid & 3;
    const int wk = tid >> 4, wnq = tid & 15;

    float acc[4][4] = {};
    const int kbeg = ks * kps, kend = kbeg + kps;

    for (int k0 = kbeg; k0 < kend; k0 += 16) {
        float4 av = *(const float4*)&A[(size_t)(bm + arow) * Kd + k0 + akq * 4];
        float4 wv = *(const float4*)&W[(size_t)(k0 + wk) * N + bn + wnq * 4];
        As[akq * 4 + 0][arow] = av.x;
        As[akq * 4 + 1][arow] = av.y;
        As[akq * 4 + 2][arow] = av.z;
        As[akq * 4 + 3][arow] = av.w;
        *(float4*)&Ws[wk][wnq * 4] = wv;
        __syncthreads();
        #pragma unroll
        for (int kk = 0; kk < 16; ++kk) {
            float4 a4 = *(const float4*)&As[kk][ty * 4];
            float4 b4 = *(const float4*)&Ws[kk][tx * 4];
            float a_[4] = {a4.x, a4.y, a4.z, a4.w};
            float b_[4] = {b4.x, b4.y, b4.z, b4.w};
            #pragma unroll
            for (int i = 0; i < 4; ++i)
                #pragma unroll
                for (int j = 0; j < 4; ++j)
                    acc[i][j] += a_[i] * b_[j];
        }
        __syncthreads();
    }

    float* Pbase = P + (size_t)ks * M * N;
    #pragma unroll
    for (int i = 0; i < 4; ++i) {
        int row = bm + ty * 4 + i;
        float4 v = {acc[i][0], acc[i][1], acc[i][2], acc[i][3]};
        *(float4*)&Pbase[(size_t)row * N + bn + tx * 4] = v;
    }
}

// ---------------------------------------------------------------------------
template<int ACT>
__global__ __launch_bounds__(256)
void reduce_k(const float* __restrict__ P, const float* __restrict__ bias,
              float* __restrict__ C, int MN, int N, int nsplit) {
    int idx = blockIdx.x * 256 + threadIdx.x;
    if (idx >= MN) return;
    float s = 0.f;
    for (int z = 0; z < nsplit; ++z) s += P[(size_t)z * MN + idx];
    if (bias) s += bias[idx & (N - 1)];
    if (ACT == 1) s = fmaxf(s, 0.f);
    C[idx] = s;
}

// ---------------------------------------------------------------------------
// masked softmax over S per batch; input = sum of 8 score slots + b_a2.
__global__ __launch_bounds__(256)
void softmax8(const float* __restrict__ scores8, const float* __restrict__ b_a2,
              const void* __restrict__ masks_raw, const int* __restrict__ flag,
              float* __restrict__ attw) {
    int b = blockIdx.x, tid = threadIdx.x;
    bool isb = (*flag) != 0;
    const unsigned char* mb = (const unsigned char*)masks_raw;
    const int* mi = (const int*)masks_raw;
    int lane = tid & 63, wv = tid >> 6;
    __shared__ float red[4], red2[4];
    float bias = b_a2[0];

    float m = -INFINITY;
    for (int s = tid; s < S_; s += 256) {
        int idx = b * S_ + s;
        float v = bias;
        #pragma unroll
        for (int z = 0; z < 8; ++z) v += scores8[(size_t)z * MS_ + idx];
        bool mk = isb ? (mb[idx] != 0) : (mi[idx] != 0);
        v = mk ? -INFINITY : v;
        attw[idx] = v;
        m = fmaxf(m, v);
    }
    #pragma unroll
    for (int off = 32; off; off >>= 1) m = fmaxf(m, __shfl_down(m, off, 64));
    if (lane == 0) red[wv] = m;
    __syncthreads();
    if (tid == 0) red[0] = fmaxf(fmaxf(red[0], red[1]), fmaxf(red[2], red[3]));
    __syncthreads();
    float Mx = red[0];

    float sum = 0.f;
    for (int s = tid; s < S_; s += 256) {
        int idx = b * S_ + s;
        float e = expf(attw[idx] - Mx);
        attw[idx] = e;
        sum += e;
    }
    #pragma unroll
    for (int off = 32; off; off >>= 1) sum += __shfl_down(sum, off, 64);
    if (lane == 0) red2[wv] = sum;
    __syncthreads();
    if (tid == 0) red2[0] = red2[0] + red2[1] + red2[2] + red2[3];
    __syncthreads();
    float inv = 1.f / red2[0];
    for (int s = tid; s < S_; s += 256) attw[b * S_ + s] *= inv;
}

// ---------------------------------------------------------------------------
// att4[z][b][h] = sum_{s in z-chunk} bf16(mm[b,s,h]) * attw[b,s]
// vectorized: each thread handles 2 h via one uint load per s.
__global__ __launch_bounds__(256)
void attended4(const unsigned short* __restrict__ mm, const float* __restrict__ attw,
               float* __restrict__ att4) {
    int b = blockIdx.x, z = blockIdx.y;
    int h2 = threadIdx.x;                 // h pair index, 256 pairs = 512 h
    __shared__ float w[128];
    int s0 = z * 128;
    if (threadIdx.x < 128) w[threadIdx.x] = attw[b * S_ + s0 + threadIdx.x];
    __syncthreads();
    const unsigned int* base =
        (const unsigned int*)mm + ((size_t)b * S_ + s0) * (HID_ / 2) + h2;
    float a0 = 0.f, a1 = 0.f;
    for (int s = 0; s < 128; ++s) {
        unsigned int u = base[(size_t)s * (HID_ / 2)];
        a0 += __uint_as_float(u << 16) * w[s];
        a1 += __uint_as_float(u & 0xffff0000u) * w[s];
    }
    float2 r = {a0, a1};
    *(float2*)&att4[((size_t)z * B_ + b) * HID_ + h2 * 2] = r;
}

// ---------------------------------------------------------------------------
__global__ __launch_bounds__(256)
void hist_avg(const float* __restrict__ ph, const int* __restrict__ hcnt,
              float* __restrict__ havg) {
    int bk = blockIdx.x;
    int cnt = hcnt[bk];
    float denom = (float)(cnt > 1 ? cnt : 1);
    const float* base = ph + (size_t)bk * HL_ * EMB_;
    for (int e = threadIdx.x; e < EMB_; e += 256) {
        float s = 0.f;
        for (int l = 0; l < cnt; ++l) s += base[l * EMB_ + e];
        havg[bk * EMB_ + e] = s / denom;
    }
}

// ---------------------------------------------------------------------------
// combine_all: reduce split-K partials of hproj(8) and sep0(16), add biases,
// relu/merge per reference, L2-normalize, dot with attended (sum of 4 chunks).
__global__ __launch_bounds__(256)
void combine_all(const float* __restrict__ skA, const float* __restrict__ skB,
                 const float* __restrict__ b_hist, const float* __restrict__ b_sep,
                 const int* __restrict__ hcnt, const float* __restrict__ att4,
                 float* __restrict__ out) {
    const int MNA = B_ * K_ * HID_;
    int bk = blockIdx.x, tid = threadIdx.x;
    int b = bk / K_;
    int cnt = hcnt[bk];
    float sq = 0.f, dt = 0.f;
    #pragma unroll
    for (int i = 0; i < HID_ / 256; ++i) {
        int h = tid + i * 256;
        size_t idx = (size_t)bk * HID_ + h;
        float hp = b_hist[h];
        #pragma unroll
        for (int z = 0; z < 8; ++z) hp += skA[(size_t)z * MNA + idx];
        hp = fmaxf(hp, 0.f);
        float sp = b_sep[h];
        #pragma unroll
        for (int z = 0; z < 16; ++z) sp += skB[(size_t)z * MNA + idx];
        float v = sp + (cnt > 0 ? hp : 0.f);
        v = fmaxf(v, 0.f);
        float at = 0.f;
        #pragma unroll
        for (int z = 0; z < 4; ++z) at += att4[((size_t)z * B_ + b) * HID_ + h];
        sq += v * v;
        dt += v * at;
    }
    #pragma unroll
    for (int off = 32; off; off >>= 1) {
        sq += __shfl_down(sq, off, 64);
        dt += __shfl_down(dt, off, 64);
    }
    __shared__ float rs[4], rd[4];
    int lane = tid & 63, wv = tid >> 6;
    if (lane == 0) { rs[wv] = sq; rd[wv] = dt; }
    __syncthreads();
    if (tid == 0) {
        float Sq = rs[0] + rs[1] + rs[2] + rs[3];
        float Dt = rd[0] + rd[1] + rd[2] + rd[3];
        float norm = fmaxf(sqrtf(Sq), 1e-12f);
        out[bk] = Dt / norm;
    }
}

// ---------------------------------------------------------------------------
extern "C" void kernel_launch(void* const* d_in, const int* in_sizes, int n_in,
                              void* d_out, int out_size, void* d_ws, size_t ws_size,
                              hipStream_t stream) {
    const float* reps     = (const float*)d_in[0];
    const float* sep_imgs = (const float*)d_in[2];
    const float* vctx     = (const float*)d_in[3];
    const float* phist    = (const float*)d_in[4];
    const int*   hcnt     = (const int*)d_in[5];
    const void*  masks    = d_in[6];
    const float* W_sep = (const float*)d_in[7];
    const float* b_sep = (const float*)d_in[8];
    const float* W_e2h = (const float*)d_in[9];
    const float* b_e2h = (const float*)d_in[10];
    const float* W_hist = (const float*)d_in[11];
    const float* b_hist = (const float*)d_in[12];
    const float* W_ctx = (const float*)d_in[13];
    const float* b_ctx = (const float*)d_in[14];
    const float* W_mm = (const float*)d_in[15];
    const float* b_mm = (const float*)d_in[16];
    const float* W_a1 = (const float*)d_in[17];
    const float* b_a1 = (const float*)d_in[18];
    const float* W_a2 = (const float*)d_in[19];
    const float* b_a2 = (const float*)d_in[20];
    float* out = (float*)d_out;

    const size_t MS = (size_t)MS_;
    const int MNA = B_ * K_ * HID_;   // 196608

    // ---- workspace layout ----
    unsigned short* actA  = (unsigned short*)d_ws;          // [MS*HID] input_reps bf16
    unsigned short* actB  = actA + MS * HID_;               // [MS*HID] mm bf16
    unsigned short* WtE2H = actB + MS * HID_;               // [512*768]
    unsigned short* WtMM  = WtE2H + (size_t)EMB_ * HID_;    // [512*512]
    unsigned short* WtA1  = WtMM + (size_t)HID_ * HID_;     // [512*512]
    float* skC    = (float*)(WtA1 + (size_t)HID_ * HID_);   // [64 * 64*512] ctx splits
    float* skA    = skC + (size_t)64 * B_ * HID_;           // [8  * 384*512] hproj splits
    float* skB    = skA + (size_t)8 * MNA;                  // [16 * 384*512] sep0 splits
    float* scores8 = skB + (size_t)16 * MNA;                // [8 * MS]
    float* attw   = scores8 + 8 * MS;                       // [B,S]
    float* att4   = attw + MS;                              // [4,B,HID]
    float* ctx    = att4 + (size_t)4 * B_ * HID_;           // [B,HID]
    float* ctx2   = ctx + B_ * HID_;                        // [B,HID]
    float* havg   = ctx2 + B_ * HID_;                       // [B*K,EMB]
    int*   flag   = (int*)(havg + (size_t)B_ * K_ * EMB_);

    // 1. prep: weight transposes (bf16) + mask dtype probe
    prep<<<dim3(EMB_ / 32, HID_ / 32, 4), 256, 0, stream>>>(
        W_e2h, W_mm, W_a1, WtE2H, WtMM, WtA1, (const unsigned char*)masks, flag);

    // 2. ctx = relu(visual_context @ W_ctx + b_ctx)   [64,512], K=12288, split-K 64
    {
        const int nsp = 64, kps = (K_ * IMG_) / nsp;
        gemm_splitk<<<dim3(8, 1, nsp), 256, 0, stream>>>(vctx, W_ctx, skC,
                                                         B_, HID_, K_ * IMG_, kps);
        reduce_k<1><<<(B_ * HID_ + 255) / 256, 256, 0, stream>>>(skC, b_ctx, ctx,
                                                                 B_ * HID_, HID_, nsp);
    }
    // 3. ctx2 = ctx @ W_mm[H:,:] + b_mm               [64,512], K=512, split-K 8
    {
        const int nsp = 8, kps = HID_ / nsp;
        gemm_splitk<<<dim3(8, 1, nsp), 256, 0, stream>>>(ctx, W_mm + (size_t)HID_ * HID_,
                                                         skC, B_, HID_, HID_, kps);
        reduce_k<0><<<(B_ * HID_ + 255) / 256, 256, 0, stream>>>(skC, b_mm, ctx2,
                                                                 B_ * HID_, HID_, nsp);
    }

    const int wave_grid = (MS_ / 64) * (HID_ / 64);    // 4096, % 8 == 0
    // 4. input_reps = relu(reps @ W_e2h + b_e2h)   fp32-in 1-wave MFMA -> actA
    gemm_wave<true, 1, false><<<wave_grid, 64, 0, stream>>>(
        reps, WtE2H, b_e2h, nullptr, 1, actA, nullptr, nullptr, MS_, HID_, EMB_);
    // 5. mm = relu(input_reps @ W_mm[:H] + ctx2[b]) -> bf16 actB
    gemm_wave<false, 1, false><<<wave_grid, 64, 0, stream>>>(
        actA, WtMM, nullptr, ctx2, S_, actB, nullptr, nullptr, MS_, HID_, HID_);
    // 6. fused t=tanh(mm@W_a1+b_a1); scores8 = partial dots with W_a2
    gemm_wave<false, 0, true><<<wave_grid, 64, 0, stream>>>(
        actB, WtA1, b_a1, nullptr, 1, actA, W_a2, scores8, MS_, ATT_, HID_);
    // 7. masked softmax (sums 8 slots + b_a2) -> attw
    softmax8<<<B_, 256, 0, stream>>>(scores8, b_a2, masks, flag, attw);
    // 8. attended partials over 4 s-chunks (vectorized)
    attended4<<<dim3(B_, 4), 256, 0, stream>>>(actB, attw, att4);
    // 9. havg
    hist_avg<<<B_ * K_, 256, 0, stream>>>(phist, hcnt, havg);
    // 10. hproj partials                              [384,512], K=768, split-K 8
    gemm_splitk<<<dim3(8, 6, 8), 256, 0, stream>>>(havg, W_hist, skA,
                                                   B_ * K_, HID_, EMB_, EMB_ / 8);
    // 11. sep0 partials                               [384,512], K=2048, split-K 16
    gemm_splitk<<<dim3(8, 6, 16), 256, 0, stream>>>(sep_imgs, W_sep, skB,
                                                    B_ * K_, HID_, IMG_, IMG_ / 16);
    // 12. combine: reduce partials, relu/merge, L2-normalize, dot -> out [384]
    combine_all<<<B_ * K_, 256, 0, stream>>>(skA, skB, b_hist, b_sep, hcnt,
                                             att4, out);
}

// Round 11
// 303.690 us; speedup vs baseline: 1.0212x; 1.0212x over previous
//
#include <hip/hip_runtime.h>
#include <math.h>

#define B_    64
#define S_    512
#define EMB_  768
#define HID_  512
#define IMG_  2048
#define ATT_  512
#define K_    6
#define HL_   20
#define MS_   (B_ * S_)            // 32768

typedef __attribute__((ext_vector_type(8))) short bf16x8;
typedef __attribute__((ext_vector_type(4))) float f32x4;

__device__ __forceinline__ unsigned short f2b(float f) {
    unsigned int u = __float_as_uint(f);
    u += 0x7fffu + ((u >> 16) & 1u);          // RNE
    return (unsigned short)(u >> 16);
}
__device__ __forceinline__ unsigned int pk_bf16(float lo, float hi) {
    unsigned int r;
    asm volatile("v_cvt_pk_bf16_f32 %0, %1, %2" : "=v"(r) : "v"(lo), "v"(hi));
    return r;
}

#define GLD_LDS16(gp, lp)                                                        \
    __builtin_amdgcn_global_load_lds(                                            \
        (const __attribute__((address_space(1))) void*)(gp),                     \
        (__attribute__((address_space(3))) void*)(lp), 16, 0, 0)

// ---------------------------------------------------------------------------
// prep: z=0..2 -> transpose+cvt of W_e2h / W_mm[:H] / W_a1 ; z=3 -> mask probe
__global__ __launch_bounds__(256)
void prep(const float* __restrict__ W_e2h, const float* __restrict__ W_mm,
          const float* __restrict__ W_a1,
          unsigned short* __restrict__ WtE2H, unsigned short* __restrict__ WtMM,
          unsigned short* __restrict__ WtA1,
          const unsigned char* __restrict__ masks, int* __restrict__ flag) {
    const int z = blockIdx.z;
    if (z == 3) {
        if (blockIdx.x != 0 || blockIdx.y != 0) return;
        __shared__ int found;
        if (threadIdx.x == 0) found = 0;
        __syncthreads();
        for (int i = threadIdx.x; i < 8192; i += 256)
            if ((i & 3) != 0 && masks[i] != 0) found = 1;
        __syncthreads();
        if (threadIdx.x == 0) *flag = found;
        return;
    }
    const float* W;
    unsigned short* Wt;
    int Kd;
    if (z == 0)      { W = W_e2h; Wt = WtE2H; Kd = EMB_; }
    else if (z == 1) { W = W_mm;  Wt = WtMM;  Kd = HID_; }
    else             { W = W_a1;  Wt = WtA1;  Kd = HID_; }
    if ((int)blockIdx.x * 32 >= Kd) return;

    __shared__ float tile[32][33];
    int k0 = blockIdx.x * 32, n0 = blockIdx.y * 32;
    int tx = threadIdx.x & 31, ty = threadIdx.x >> 5;   // 32 x 8
    #pragma unroll
    for (int i = 0; i < 4; ++i)
        tile[ty + i * 8][tx] = W[(size_t)(k0 + ty + i * 8) * HID_ + n0 + tx];
    __syncthreads();
    #pragma unroll
    for (int i = 0; i < 4; ++i)
        Wt[(size_t)(n0 + ty + i * 8) * Kd + k0 + tx] = f2b(tile[tx][ty + i * 8]);
}

// ---------------------------------------------------------------------------
// XCD-chunked bijective swizzle within the gemm sub-grid (nwg % 8 == 0).
__device__ __forceinline__ void tile_coords(int bid, int nwg, int N, int& bm, int& bn) {
    const int cpx = nwg >> 3;
    const int lid = (bid & 7) * cpx + (bid >> 3);
    const int ntl = N >> 7;
    bn = (lid % ntl) << 7;
    bm = (lid / ntl) << 7;
}

// ---------------------------------------------------------------------------
// Round-5 verbatim GEMM body (best measured: 262 us pipeline).
// 128x128 tile, BK=64, dbuf LDS (64 KB), stage-early + __syncthreads,
// XOR-swizzled LDS layout via pre-swizzled global source.
// AF32: A fp32 reg-staged (global->reg->cvt_pk->ds_write). SCORE: tanh+W_a2
// partial-score epilogue. 4 waves (2x2), 4x4 16x16x32 fragments.
template<bool AF32, int ACT, bool SCORE>
__device__ __forceinline__
void gemm_body(unsigned char* smem, int bid, int nwg,
               const void* __restrict__ Av, const unsigned short* __restrict__ Bt,
               const float* __restrict__ bias, const float* __restrict__ row_add,
               int row_div, unsigned short* __restrict__ Co,
               const float* __restrict__ W_a2, float* __restrict__ scores8,
               int M, int N, int Kd) {
    unsigned short* Als = (unsigned short*)smem;          // [2][128*64]
    unsigned short* Bls = Als + 2 * 128 * 64;             // [2][128*64]
    const int tid = threadIdx.x;
    int bm, bn; tile_coords(bid, nwg, N, bm, bn);
    const int lane = tid & 63, wid = tid >> 6;
    const int wr = wid >> 1, wc = wid & 1;
    const int fr = lane & 15, hi = lane >> 4;

    const unsigned short* Ab = (const unsigned short*)Av;
    const float* Af = (const float*)Av;

    f32x4 acc[4][4] = {};
    int srow[4], lcol[4], scol[4];
    #pragma unroll
    for (int c = 0; c < 4; ++c) {
        int g = c * 256 + tid;
        srow[c] = g >> 3;
        lcol[c] = g & 7;
        scol[c] = lcol[c] ^ (srow[c] & 7);
    }

    float4 ra[8];

    auto stageA_lds = [&](int t, int buf) {
        #pragma unroll
        for (int c = 0; c < 4; ++c) {
            int g = c * 256 + tid;
            GLD_LDS16(Ab + (size_t)(bm + srow[c]) * Kd + t * 64 + scol[c] * 8,
                      &Als[buf * 8192 + g * 8]);
        }
    };
    auto stageB_lds = [&](int t, int buf) {
        #pragma unroll
        for (int c = 0; c < 4; ++c) {
            int g = c * 256 + tid;
            GLD_LDS16(Bt + (size_t)(bn + srow[c]) * Kd + t * 64 + scol[c] * 8,
                      &Bls[buf * 8192 + g * 8]);
        }
    };
    auto loadA = [&](int t) {
        #pragma unroll
        for (int c = 0; c < 4; ++c) {
            const float* p = Af + (size_t)(bm + srow[c]) * Kd + t * 64 + lcol[c] * 8;
            ra[2 * c]     = *(const float4*)p;
            ra[2 * c + 1] = *(const float4*)(p + 4);
        }
    };
    auto writeA = [&](int buf) {
        #pragma unroll
        for (int c = 0; c < 4; ++c) {
            uint4 u;
            u.x = pk_bf16(ra[2*c].x,   ra[2*c].y);
            u.y = pk_bf16(ra[2*c].z,   ra[2*c].w);
            u.z = pk_bf16(ra[2*c+1].x, ra[2*c+1].y);
            u.w = pk_bf16(ra[2*c+1].z, ra[2*c+1].w);
            *(uint4*)&Als[buf * 8192 + (srow[c] * 8 + scol[c]) * 8] = u;
        }
    };
    auto compute = [&](int buf) {
        #pragma unroll
        for (int kk = 0; kk < 2; ++kk) {
            bf16x8 af[4], bv[4];
            #pragma unroll
            for (int m = 0; m < 4; ++m) {
                int r = wr * 64 + m * 16 + fr;
                int sc = (kk * 4 + hi) ^ (fr & 7);
                af[m] = *(const bf16x8*)&Als[buf * 8192 + r * 64 + sc * 8];
            }
            #pragma unroll
            for (int n = 0; n < 4; ++n) {
                int r = wc * 64 + n * 16 + fr;
                int sc = (kk * 4 + hi) ^ (fr & 7);
                bv[n] = *(const bf16x8*)&Bls[buf * 8192 + r * 64 + sc * 8];
            }
            #pragma unroll
            for (int m = 0; m < 4; ++m)
                #pragma unroll
                for (int n = 0; n < 4; ++n)
                    acc[m][n] = __builtin_amdgcn_mfma_f32_16x16x32_bf16(af[m], bv[n], acc[m][n], 0, 0, 0);
        }
    };

    const int nt = Kd >> 6;

    // prologue: tile 0
    if constexpr (AF32) {
        loadA(0);
        stageB_lds(0, 0);
        writeA(0);
    } else {
        stageA_lds(0, 0);
        stageB_lds(0, 0);
    }
    __syncthreads();

    for (int t = 0; t < nt; ++t) {
        const int buf = t & 1;
        const bool pf = (t + 1 < nt);
        if (pf) {
            if constexpr (AF32) {
                loadA(t + 1);
                stageB_lds(t + 1, buf ^ 1);
            } else {
                stageA_lds(t + 1, buf ^ 1);
                stageB_lds(t + 1, buf ^ 1);
            }
        }
        compute(buf);
        if constexpr (AF32) {
            if (pf) writeA(buf ^ 1);
        }
        __syncthreads();
    }

    // epilogue
    if (SCORE) {
        float ba[4], wa[4];
        #pragma unroll
        for (int n = 0; n < 4; ++n) {
            int col = bn + wc * 64 + n * 16 + fr;
            ba[n] = bias[col];
            wa[n] = W_a2[col];
        }
        const int slot = (bn >> 7) * 2 + wc;
        #pragma unroll
        for (int m = 0; m < 4; ++m) {
            #pragma unroll
            for (int r = 0; r < 4; ++r) {
                float p = 0.f;
                #pragma unroll
                for (int n = 0; n < 4; ++n)
                    p += tanhf(acc[m][n][r] + ba[n]) * wa[n];
                p += __shfl_xor(p, 1, 64);
                p += __shfl_xor(p, 2, 64);
                p += __shfl_xor(p, 4, 64);
                p += __shfl_xor(p, 8, 64);
                if (fr == 0)
                    scores8[(size_t)slot * M + bm + wr * 64 + m * 16 + hi * 4 + r] = p;
            }
        }
    } else {
        #pragma unroll
        for (int m = 0; m < 4; ++m) {
            #pragma unroll
            for (int n = 0; n < 4; ++n) {
                int col = bn + wc * 64 + n * 16 + fr;
                float badd = bias ? bias[col] : 0.f;
                #pragma unroll
                for (int r = 0; r < 4; ++r) {
                    int row = bm + wr * 64 + m * 16 + hi * 4 + r;
                    float x = acc[m][n][r] + badd;
                    if (row_add) x += row_add[(size_t)(row / row_div) * N + col];
                    if (ACT == 1) x = fmaxf(x, 0.f);
                    Co[(size_t)row * N + col] = f2b(x);
                }
            }
        }
    }
}

// ---------------------------------------------------------------------------
// split-K partial fp32 GEMM body: P[z, m, n] = A[m, kz..kz+kps) @ W[.., n]
__device__ __forceinline__
void splitk_body(unsigned char* smem, int bx, int by, int bz,
                 const float* __restrict__ A, const float* __restrict__ W,
                 float* __restrict__ P, int M, int N, int Kd, int kps) {
    float (*As)[68] = (float(*)[68])smem;                 // 16x68 f32
    float (*Ws)[64] = (float(*)[64])(smem + 16 * 68 * 4); // 16x64 f32
    const int tid = threadIdx.x;
    const int bm = by * 64, bn = bx * 64;
    const int tx = tid & 15, ty = tid >> 4;
    const int arow = tid >> 2, akq = tid & 3;
    const int wk = tid >> 4, wnq = tid & 15;

    float acc[4][4] = {};
    const int kbeg = bz * kps, kend = kbeg + kps;

    for (int k0 = kbeg; k0 < kend; k0 += 16) {
        float4 av = *(const float4*)&A[(size_t)(bm + arow) * Kd + k0 + akq * 4];
        float4 wv = *(const float4*)&W[(size_t)(k0 + wk) * N + bn + wnq * 4];
        As[akq * 4 + 0][arow] = av.x;
        As[akq * 4 + 1][arow] = av.y;
        As[akq * 4 + 2][arow] = av.z;
        As[akq * 4 + 3][arow] = av.w;
        *(float4*)&Ws[wk][wnq * 4] = wv;
        __syncthreads();
        #pragma unroll
        for (int kk = 0; kk < 16; ++kk) {
            float4 a4 = *(const float4*)&As[kk][ty * 4];
            float4 b4 = *(const float4*)&Ws[kk][tx * 4];
            float a_[4] = {a4.x, a4.y, a4.z, a4.w};
            float b_[4] = {b4.x, b4.y, b4.z, b4.w};
            #pragma unroll
            for (int i = 0; i < 4; ++i)
                #pragma unroll
                for (int j = 0; j < 4; ++j)
                    acc[i][j] += a_[i] * b_[j];
        }
        __syncthreads();
    }

    float* Pbase = P + (size_t)bz * M * N;
    #pragma unroll
    for (int i = 0; i < 4; ++i) {
        int row = bm + ty * 4 + i;
        float4 v = {acc[i][0], acc[i][1], acc[i][2], acc[i][3]};
        *(float4*)&Pbase[(size_t)row * N + bn + tx * 4] = v;
    }
}

// ---------------------------------------------------------------------------
// hist average body: one block per (b,k) pair.
__device__ __forceinline__
void hist_body(const float* __restrict__ ph, const int* __restrict__ hcnt,
               float* __restrict__ havg, int bk) {
    int cnt = hcnt[bk];
    float denom = (float)(cnt > 1 ? cnt : 1);
    const float* base = ph + (size_t)bk * HL_ * EMB_;
    for (int e = threadIdx.x; e < EMB_; e += 256) {
        float s = 0.f;
        for (int l = 0; l < cnt; ++l) s += base[l * EMB_ + e];
        havg[bk * EMB_ + e] = s / denom;
    }
}

// ---------------------------------------------------------------------------
// MEGA1: [0,1024) GEMM3 (fp32-A) | [1024,1536) ctx split-K | [1536,1920)
// hist_avg | [1920,2688) sep0 split-K.
__global__ __launch_bounds__(256)
void mega1(const float* __restrict__ reps, const unsigned short* __restrict__ WtE2H,
           const float* __restrict__ b_e2h, unsigned short* __restrict__ actA,
           const float* __restrict__ vctx, const float* __restrict__ W_ctx,
           float* __restrict__ skC,
           const float* __restrict__ phist, const int* __restrict__ hcnt,
           float* __restrict__ havg,
           const float* __restrict__ sep_imgs, const float* __restrict__ W_sep,
           float* __restrict__ skB) {
    __shared__ __align__(16) unsigned char smem[65536];
    const int bid = blockIdx.x;
    if (bid < 1024) {
        gemm_body<true, 1, false>(smem, bid, 1024, reps, WtE2H, b_e2h, nullptr, 1,
                                  actA, nullptr, nullptr, MS_, HID_, EMB_);
    } else if (bid < 1536) {
        int b = bid - 1024;                     // 8 x 64 splits, kps=192
        splitk_body(smem, b & 7, 0, b >> 3, vctx, W_ctx, skC, B_, HID_,
                    K_ * IMG_, (K_ * IMG_) / 64);
    } else if (bid < 1920) {
        hist_body(phist, hcnt, havg, bid - 1536);
    } else {
        int b = bid - 1920;                     // 8 x 6 x 16 splits, kps=128
        splitk_body(smem, b & 7, (b >> 3) % 6, b / 48, sep_imgs, W_sep, skB,
                    B_ * K_, HID_, IMG_, IMG_ / 16);
    }
}

// ---------------------------------------------------------------------------
// MEGA2: [0,1024) GEMM4 (bf16, +ctx2 row_add) | [1024,1408) hproj split-K.
__global__ __launch_bounds__(256)
void mega2(const unsigned short* __restrict__ actA, const unsigned short* __restrict__ WtMM,
           const float* __restrict__ ctx2, unsigned short* __restrict__ actB,
           const float* __restrict__ havg, const float* __restrict__ W_hist,
           float* __restrict__ skA) {
    __shared__ __align__(16) unsigned char smem[65536];
    const int bid = blockIdx.x;
    if (bid < 1024) {
        gemm_body<false, 1, false>(smem, bid, 1024, actA, WtMM, nullptr, ctx2, S_,
                                   actB, nullptr, nullptr, MS_, HID_, HID_);
    } else {
        int b = bid - 1024;                     // 8 x 6 x 8 splits, kps=96
        splitk_body(smem, b & 7, (b >> 3) % 6, b / 48, havg, W_hist, skA,
                    B_ * K_, HID_, EMB_, EMB_ / 8);
    }
}

// ---------------------------------------------------------------------------
// GEMM5 + score fusion (standalone, 1024 blocks).
__global__ __launch_bounds__(256)
void gemm_score(const unsigned short* __restrict__ actB, const unsigned short* __restrict__ WtA1,
                const float* __restrict__ b_a1, const float* __restrict__ W_a2,
                float* __restrict__ scores8) {
    __shared__ __align__(16) unsigned char smem[65536];
    gemm_body<false, 0, true>(smem, blockIdx.x, 1024, actB, WtA1, b_a1, nullptr, 1,
                              nullptr, W_a2, scores8, MS_, ATT_, HID_);
}

// ---------------------------------------------------------------------------
// standalone split-K for the ctx2 chain (small).
__global__ __launch_bounds__(256)
void gemm_splitk(const float* __restrict__ A, const float* __restrict__ W,
                 float* __restrict__ P, int M, int N, int Kd, int kps) {
    __shared__ __align__(16) unsigned char smem[16 * 68 * 4 + 16 * 64 * 4];
    splitk_body(smem, blockIdx.x, blockIdx.y, blockIdx.z, A, W, P, M, N, Kd, kps);
}

// ---------------------------------------------------------------------------
template<int ACT>
__global__ __launch_bounds__(256)
void reduce_k(const float* __restrict__ P, const float* __restrict__ bias,
              float* __restrict__ C, int MN, int N, int nsplit) {
    int idx = blockIdx.x * 256 + threadIdx.x;
    if (idx >= MN) return;
    float s = 0.f;
    for (int z = 0; z < nsplit; ++z) s += P[(size_t)z * MN + idx];
    if (bias) s += bias[idx & (N - 1)];
    if (ACT == 1) s = fmaxf(s, 0.f);
    C[idx] = s;
}

// ---------------------------------------------------------------------------
// masked softmax over S per batch; input = sum of 8 score slots + b_a2.
__global__ __launch_bounds__(256)
void softmax8(const float* __restrict__ scores8, const float* __restrict__ b_a2,
              const void* __restrict__ masks_raw, const int* __restrict__ flag,
              float* __restrict__ attw) {
    int b = blockIdx.x, tid = threadIdx.x;
    bool isb = (*flag) != 0;
    const unsigned char* mb = (const unsigned char*)masks_raw;
    const int* mi = (const int*)masks_raw;
    int lane = tid & 63, wv = tid >> 6;
    __shared__ float red[4], red2[4];
    float bias = b_a2[0];

    float m = -INFINITY;
    for (int s = tid; s < S_; s += 256) {
        int idx = b * S_ + s;
        float v = bias;
        #pragma unroll
        for (int z = 0; z < 8; ++z) v += scores8[(size_t)z * MS_ + idx];
        bool mk = isb ? (mb[idx] != 0) : (mi[idx] != 0);
        v = mk ? -INFINITY : v;
        attw[idx] = v;
        m = fmaxf(m, v);
    }
    #pragma unroll
    for (int off = 32; off; off >>= 1) m = fmaxf(m, __shfl_down(m, off, 64));
    if (lane == 0) red[wv] = m;
    __syncthreads();
    if (tid == 0) red[0] = fmaxf(fmaxf(red[0], red[1]), fmaxf(red[2], red[3]));
    __syncthreads();
    float Mx = red[0];

    float sum = 0.f;
    for (int s = tid; s < S_; s += 256) {
        int idx = b * S_ + s;
        float e = expf(attw[idx] - Mx);
        attw[idx] = e;
        sum += e;
    }
    #pragma unroll
    for (int off = 32; off; off >>= 1) sum += __shfl_down(sum, off, 64);
    if (lane == 0) red2[wv] = sum;
    __syncthreads();
    if (tid == 0) red2[0] = red2[0] + red2[1] + red2[2] + red2[3];
    __syncthreads();
    float inv = 1.f / red2[0];
    for (int s = tid; s < S_; s += 256) attw[b * S_ + s] *= inv;
}

// ---------------------------------------------------------------------------
// att4[z][b][h] = sum_{s in z-chunk} bf16(mm[b,s,h]) * attw[b,s]
__global__ __launch_bounds__(256)
void attended4(const unsigned short* __restrict__ mm, const float* __restrict__ attw,
               float* __restrict__ att4) {
    int b = blockIdx.x, z = blockIdx.y;
    int h2 = threadIdx.x;                 // h pair index, 256 pairs = 512 h
    __shared__ float w[128];
    int s0 = z * 128;
    if (threadIdx.x < 128) w[threadIdx.x] = attw[b * S_ + s0 + threadIdx.x];
    __syncthreads();
    const unsigned int* base =
        (const unsigned int*)mm + ((size_t)b * S_ + s0) * (HID_ / 2) + h2;
    float a0 = 0.f, a1 = 0.f;
    for (int s = 0; s < 128; ++s) {
        unsigned int u = base[(size_t)s * (HID_ / 2)];
        a0 += __uint_as_float(u << 16) * w[s];
        a1 += __uint_as_float(u & 0xffff0000u) * w[s];
    }
    float2 r = {a0, a1};
    *(float2*)&att4[((size_t)z * B_ + b) * HID_ + h2 * 2] = r;
}

// ---------------------------------------------------------------------------
// combine_all: reduce split-K partials of hproj(8) and sep0(16), add biases,
// relu/merge per reference, L2-normalize, dot with attended (sum of 4 chunks).
__global__ __launch_bounds__(256)
void combine_all(const float* __restrict__ skA, const float* __restrict__ skB,
                 const float* __restrict__ b_hist, const float* __restrict__ b_sep,
                 const int* __restrict__ hcnt, const float* __restrict__ att4,
                 float* __restrict__ out) {
    const int MNA = B_ * K_ * HID_;
    int bk = blockIdx.x, tid = threadIdx.x;
    int b = bk / K_;
    int cnt = hcnt[bk];
    float sq = 0.f, dt = 0.f;
    #pragma unroll
    for (int i = 0; i < HID_ / 256; ++i) {
        int h = tid + i * 256;
        size_t idx = (size_t)bk * HID_ + h;
        float hp = b_hist[h];
        #pragma unroll
        for (int z = 0; z < 8; ++z) hp += skA[(size_t)z * MNA + idx];
        hp = fmaxf(hp, 0.f);
        float sp = b_sep[h];
        #pragma unroll
        for (int z = 0; z < 16; ++z) sp += skB[(size_t)z * MNA + idx];
        float v = sp + (cnt > 0 ? hp : 0.f);
        v = fmaxf(v, 0.f);
        float at = 0.f;
        #pragma unroll
        for (int z = 0; z < 4; ++z) at += att4[((size_t)z * B_ + b) * HID_ + h];
        sq += v * v;
        dt += v * at;
    }
    #pragma unroll
    for (int off = 32; off; off >>= 1) {
        sq += __shfl_down(sq, off, 64);
        dt += __shfl_down(dt, off, 64);
    }
    __shared__ float rs[4], rd[4];
    int lane = tid & 63, wv = tid >> 6;
    if (lane == 0) { rs[wv] = sq; rd[wv] = dt; }
    __syncthreads();
    if (tid == 0) {
        float Sq = rs[0] + rs[1] + rs[2] + rs[3];
        float Dt = rd[0] + rd[1] + rd[2] + rd[3];
        float norm = fmaxf(sqrtf(Sq), 1e-12f);
        out[bk] = Dt / norm;
    }
}

// ---------------------------------------------------------------------------
extern "C" void kernel_launch(void* const* d_in, const int* in_sizes, int n_in,
                              void* d_out, int out_size, void* d_ws, size_t ws_size,
                              hipStream_t stream) {
    const float* reps     = (const float*)d_in[0];
    const float* sep_imgs = (const float*)d_in[2];
    const float* vctx     = (const float*)d_in[3];
    const float* phist    = (const float*)d_in[4];
    const int*   hcnt     = (const int*)d_in[5];
    const void*  masks    = d_in[6];
    const float* W_sep = (const float*)d_in[7];
    const float* b_sep = (const float*)d_in[8];
    const float* W_e2h = (const float*)d_in[9];
    const float* b_e2h = (const float*)d_in[10];
    const float* W_hist = (const float*)d_in[11];
    const float* b_hist = (const float*)d_in[12];
    const float* W_ctx = (const float*)d_in[13];
    const float* b_ctx = (const float*)d_in[14];
    const float* W_mm = (const float*)d_in[15];
    const float* b_mm = (const float*)d_in[16];
    const float* W_a1 = (const float*)d_in[17];
    const float* b_a1 = (const float*)d_in[18];
    const float* W_a2 = (const float*)d_in[19];
    const float* b_a2 = (const float*)d_in[20];
    float* out = (float*)d_out;

    const size_t MS = (size_t)MS_;
    const int MNA = B_ * K_ * HID_;   // 196608

    // ---- workspace layout ----
    unsigned short* actA  = (unsigned short*)d_ws;          // [MS*HID] input_reps bf16
    unsigned short* actB  = actA + MS * HID_;               // [MS*HID] mm bf16
    unsigned short* WtE2H = actB + MS * HID_;               // [512*768]
    unsigned short* WtMM  = WtE2H + (size_t)EMB_ * HID_;    // [512*512]
    unsigned short* WtA1  = WtMM + (size_t)HID_ * HID_;     // [512*512]
    float* skC    = (float*)(WtA1 + (size_t)HID_ * HID_);   // [64 * 64*512] ctx splits
    float* skA    = skC + (size_t)64 * B_ * HID_;           // [8  * 384*512] hproj splits
    float* skB    = skA + (size_t)8 * MNA;                  // [16 * 384*512] sep0 splits
    float* scores8 = skB + (size_t)16 * MNA;                // [8 * MS]
    float* attw   = scores8 + 8 * MS;                       // [B,S]
    float* att4   = attw + MS;                              // [4,B,HID]
    float* ctx    = att4 + (size_t)4 * B_ * HID_;           // [B,HID]
    float* ctx2   = ctx + B_ * HID_;                        // [B,HID]
    float* havg   = ctx2 + B_ * HID_;                       // [B*K,EMB]
    int*   flag   = (int*)(havg + (size_t)B_ * K_ * EMB_);

    // D0. prep: weight transposes (bf16) + mask dtype probe
    prep<<<dim3(EMB_ / 32, HID_ / 32, 4), 256, 0, stream>>>(
        W_e2h, W_mm, W_a1, WtE2H, WtMM, WtA1, (const unsigned char*)masks, flag);

    // D1. MEGA1: GEMM3 | ctx split-K | hist_avg | sep0 split-K    (2688 blocks)
    mega1<<<2688, 256, 0, stream>>>(reps, WtE2H, b_e2h, actA,
                                    vctx, W_ctx, skC,
                                    phist, hcnt, havg,
                                    sep_imgs, W_sep, skB);

    // D2. ctx = relu(sum skC + b_ctx)
    reduce_k<1><<<(B_ * HID_ + 255) / 256, 256, 0, stream>>>(skC, b_ctx, ctx,
                                                             B_ * HID_, HID_, 64);
    // D3. ctx2 split-K: ctx @ W_mm[H:,:]   [64,512], K=512, 8 splits
    gemm_splitk<<<dim3(8, 1, 8), 256, 0, stream>>>(ctx, W_mm + (size_t)HID_ * HID_,
                                                   skC, B_, HID_, HID_, HID_ / 8);
    // D4. ctx2 = sum skC + b_mm
    reduce_k<0><<<(B_ * HID_ + 255) / 256, 256, 0, stream>>>(skC, b_mm, ctx2,
                                                             B_ * HID_, HID_, 8);

    // D5. MEGA2: GEMM4 (+ctx2 row_add) | hproj split-K            (1408 blocks)
    mega2<<<1408, 256, 0, stream>>>(actA, WtMM, ctx2, actB, havg, W_hist, skA);

    // D6. GEMM5 fused with score partials
    gemm_score<<<1024, 256, 0, stream>>>(actB, WtA1, b_a1, W_a2, scores8);

    // D7. masked softmax (sums 8 slots + b_a2) -> attw
    softmax8<<<B_, 256, 0, stream>>>(scores8, b_a2, masks, flag, attw);
    // D8. attended partials over 4 s-chunks
    attended4<<<dim3(B_, 4), 256, 0, stream>>>(actB, attw, att4);
    // D9. combine: reduce partials, relu/merge, L2-normalize, dot -> out [384]
    combine_all<<<B_ * K_, 256, 0, stream>>>(skA, skB, b_hist, b_sep, hcnt,
                                             att4, out);
}

// Round 12
// 262.255 us; speedup vs baseline: 1.1826x; 1.1580x over previous
//
#include <hip/hip_runtime.h>
#include <math.h>

#define B_    64
#define S_    512
#define EMB_  768
#define HID_  512
#define IMG_  2048
#define ATT_  512
#define K_    6
#define HL_   20
#define MS_   (B_ * S_)            // 32768

typedef __attribute__((ext_vector_type(8))) short bf16x8;
typedef __attribute__((ext_vector_type(4))) float f32x4;

__device__ __forceinline__ unsigned short f2b(float f) {
    unsigned int u = __float_as_uint(f);
    u += 0x7fffu + ((u >> 16) & 1u);          // RNE
    return (unsigned short)(u >> 16);
}
__device__ __forceinline__ unsigned int pk_bf16(float lo, float hi) {
    unsigned int r;
    asm volatile("v_cvt_pk_bf16_f32 %0, %1, %2" : "=v"(r) : "v"(lo), "v"(hi));
    return r;
}

#define GLD_LDS16(gp, lp)                                                        \
    __builtin_amdgcn_global_load_lds(                                            \
        (const __attribute__((address_space(1))) void*)(gp),                     \
        (__attribute__((address_space(3))) void*)(lp), 16, 0, 0)

// ---------------------------------------------------------------------------
// prep: z=0..2 -> transpose+cvt of W_e2h / W_mm[:H] / W_a1 ; z=3 -> mask probe
__global__ __launch_bounds__(256)
void prep(const float* __restrict__ W_e2h, const float* __restrict__ W_mm,
          const float* __restrict__ W_a1,
          unsigned short* __restrict__ WtE2H, unsigned short* __restrict__ WtMM,
          unsigned short* __restrict__ WtA1,
          const unsigned char* __restrict__ masks, int* __restrict__ flag) {
    const int z = blockIdx.z;
    if (z == 3) {
        if (blockIdx.x != 0 || blockIdx.y != 0) return;
        __shared__ int found;
        if (threadIdx.x == 0) found = 0;
        __syncthreads();
        for (int i = threadIdx.x; i < 8192; i += 256)
            if ((i & 3) != 0 && masks[i] != 0) found = 1;
        __syncthreads();
        if (threadIdx.x == 0) *flag = found;
        return;
    }
    const float* W;
    unsigned short* Wt;
    int Kd;
    if (z == 0)      { W = W_e2h; Wt = WtE2H; Kd = EMB_; }
    else if (z == 1) { W = W_mm;  Wt = WtMM;  Kd = HID_; }
    else             { W = W_a1;  Wt = WtA1;  Kd = HID_; }
    if ((int)blockIdx.x * 32 >= Kd) return;

    __shared__ float tile[32][33];
    int k0 = blockIdx.x * 32, n0 = blockIdx.y * 32;
    int tx = threadIdx.x & 31, ty = threadIdx.x >> 5;   // 32 x 8
    #pragma unroll
    for (int i = 0; i < 4; ++i)
        tile[ty + i * 8][tx] = W[(size_t)(k0 + ty + i * 8) * HID_ + n0 + tx];
    __syncthreads();
    #pragma unroll
    for (int i = 0; i < 4; ++i)
        Wt[(size_t)(n0 + ty + i * 8) * Kd + k0 + tx] = f2b(tile[tx][ty + i * 8]);
}

// ---------------------------------------------------------------------------
// 256x256-tile 2-phase MFMA GEMM: 8 waves (2Mx4N), BK=64, dbuf LDS (128 KB),
// stage-early + __syncthreads (round-5 proven sync), XOR-swizzled LDS via
// pre-swizzled global source, XCD-chunked block swizzle (nwg % 8 == 0).
// Per wave: 128x64 output = acc[8][4] f32x4. Grid = (M/256)*(N/256) blocks.
// AF32: A fp32 reg-staged (global->reg->cvt_pk->ds_write).
// SCORE: tanh+W_a2 partial-score epilogue (slot = bn/64 + wc, 8 slots).
template<bool AF32, int ACT, bool SCORE>
__global__ __launch_bounds__(512)
void gemm256(const void* __restrict__ Av, const unsigned short* __restrict__ Bt,
             const float* __restrict__ bias, const float* __restrict__ row_add,
             int row_div, unsigned short* __restrict__ Co,
             const float* __restrict__ W_a2, float* __restrict__ scores8,
             int M, int N, int Kd) {
    __shared__ unsigned short Als[2][256 * 64];   // 64 KB
    __shared__ unsigned short Bls[2][256 * 64];   // 64 KB
    const int tid = threadIdx.x;

    const int nwg = gridDim.x;                    // % 8 == 0
    const int cpx = nwg >> 3;
    const int lid = ((int)blockIdx.x & 7) * cpx + ((int)blockIdx.x >> 3);
    const int ntl = N >> 8;
    const int bn = (lid % ntl) << 8;
    const int bm = (lid / ntl) << 8;

    const int lane = tid & 63, wid = tid >> 6;    // 8 waves
    const int wr = wid >> 2, wc = wid & 3;        // 2 x 4
    const int fr = lane & 15, hi = lane >> 4;

    const unsigned short* Ab = (const unsigned short*)Av;
    const float* Af = (const float*)Av;

    f32x4 acc[8][4] = {};

    // staging geometry: tile 256 rows x 8 col16-slots = 2048 chunks, 4/thread
    int srow[4], lcol[4], scol[4];
    #pragma unroll
    for (int c = 0; c < 4; ++c) {
        int g = c * 512 + tid;
        srow[c] = g >> 3;
        lcol[c] = g & 7;
        scol[c] = lcol[c] ^ (srow[c] & 7);
    }

    float4 ra[8];   // fp32-A staging: 4 chunks x 2 float4

    auto stageA_lds = [&](int t, int buf) {       // bf16 A: 4 gld_lds
        #pragma unroll
        for (int c = 0; c < 4; ++c) {
            int g = c * 512 + tid;
            GLD_LDS16(Ab + (size_t)(bm + srow[c]) * Kd + t * 64 + scol[c] * 8,
                      &Als[buf][g * 8]);
        }
    };
    auto stageB_lds = [&](int t, int buf) {       // 4 gld_lds
        #pragma unroll
        for (int c = 0; c < 4; ++c) {
            int g = c * 512 + tid;
            GLD_LDS16(Bt + (size_t)(bn + srow[c]) * Kd + t * 64 + scol[c] * 8,
                      &Bls[buf][g * 8]);
        }
    };
    auto loadA = [&](int t) {                     // fp32 A -> regs (8 float4)
        #pragma unroll
        for (int c = 0; c < 4; ++c) {
            const float* p = Af + (size_t)(bm + srow[c]) * Kd + t * 64 + scol[c] * 8;
            ra[2 * c]     = *(const float4*)p;
            ra[2 * c + 1] = *(const float4*)(p + 4);
        }
    };
    auto writeA = [&](int buf) {                  // cvt + ds_write (linear dest)
        #pragma unroll
        for (int c = 0; c < 4; ++c) {
            int g = c * 512 + tid;
            uint4 u;
            u.x = pk_bf16(ra[2*c].x,   ra[2*c].y);
            u.y = pk_bf16(ra[2*c].z,   ra[2*c].w);
            u.z = pk_bf16(ra[2*c+1].x, ra[2*c+1].y);
            u.w = pk_bf16(ra[2*c+1].z, ra[2*c+1].w);
            *(uint4*)&Als[buf][g * 8] = u;
        }
    };
    auto compute = [&](int buf) {
        #pragma unroll
        for (int kk = 0; kk < 2; ++kk) {
            bf16x8 af[8], bv[4];
            #pragma unroll
            for (int m = 0; m < 8; ++m) {
                int r = wr * 128 + m * 16 + fr;
                int sc = (kk * 4 + hi) ^ (r & 7);
                af[m] = *(const bf16x8*)&Als[buf][r * 64 + sc * 8];
            }
            #pragma unroll
            for (int n = 0; n < 4; ++n) {
                int r = wc * 64 + n * 16 + fr;
                int sc = (kk * 4 + hi) ^ (r & 7);
                bv[n] = *(const bf16x8*)&Bls[buf][r * 64 + sc * 8];
            }
            #pragma unroll
            for (int m = 0; m < 8; ++m)
                #pragma unroll
                for (int n = 0; n < 4; ++n)
                    acc[m][n] = __builtin_amdgcn_mfma_f32_16x16x32_bf16(af[m], bv[n], acc[m][n], 0, 0, 0);
        }
    };

    const int nt = Kd >> 6;   // 12 (K=768) or 8 (K=512)

    // prologue: tile 0
    if constexpr (AF32) {
        loadA(0);
        stageB_lds(0, 0);
        writeA(0);            // compiler inserts counted vmcnt for ra
    } else {
        stageA_lds(0, 0);
        stageB_lds(0, 0);
    }
    __syncthreads();

    for (int t = 0; t < nt; ++t) {
        const int buf = t & 1;
        const bool pf = (t + 1 < nt);
        if (pf) {
            if constexpr (AF32) {
                loadA(t + 1);
                stageB_lds(t + 1, buf ^ 1);
            } else {
                stageA_lds(t + 1, buf ^ 1);
                stageB_lds(t + 1, buf ^ 1);
            }
        }
        compute(buf);
        if constexpr (AF32) {
            if (pf) writeA(buf ^ 1);
        }
        __syncthreads();      // drains t+1 stage (hidden under compute)
    }

    // --- epilogue ---------------------------------------------------------
    if (SCORE) {
        float ba[4], wa[4];
        #pragma unroll
        for (int n = 0; n < 4; ++n) {
            int col = bn + wc * 64 + n * 16 + fr;
            ba[n] = bias[col];
            wa[n] = W_a2[col];
        }
        const int slot = (bn >> 6) + wc;          // 8 slots over N=512
        #pragma unroll
        for (int m = 0; m < 8; ++m) {
            #pragma unroll
            for (int r = 0; r < 4; ++r) {
                float p = 0.f;
                #pragma unroll
                for (int n = 0; n < 4; ++n)
                    p += tanhf(acc[m][n][r] + ba[n]) * wa[n];
                p += __shfl_xor(p, 1, 64);
                p += __shfl_xor(p, 2, 64);
                p += __shfl_xor(p, 4, 64);
                p += __shfl_xor(p, 8, 64);
                if (fr == 0)
                    scores8[(size_t)slot * M + bm + wr * 128 + m * 16 + hi * 4 + r] = p;
            }
        }
    } else {
        #pragma unroll
        for (int m = 0; m < 8; ++m) {
            #pragma unroll
            for (int n = 0; n < 4; ++n) {
                int col = bn + wc * 64 + n * 16 + fr;
                float badd = bias ? bias[col] : 0.f;
                #pragma unroll
                for (int r = 0; r < 4; ++r) {
                    int row = bm + wr * 128 + m * 16 + hi * 4 + r;
                    float x = acc[m][n][r] + badd;
                    if (row_add) x += row_add[(size_t)(row / row_div) * N + col];
                    if (ACT == 1) x = fmaxf(x, 0.f);
                    Co[(size_t)row * N + col] = f2b(x);
                }
            }
        }
    }
}

// ---------------------------------------------------------------------------
// split-K partial fp32 GEMM: P[z, m, n] = A[m, kz..kz+kps) @ W[.., n]
__global__ __launch_bounds__(256)
void gemm_splitk(const float* __restrict__ A, const float* __restrict__ W,
                 float* __restrict__ P, int M, int N, int Kd, int kps) {
    __shared__ float As[16][68];
    __shared__ float Ws[16][64];
    const int tid = threadIdx.x;
    const int bm = blockIdx.y * 64, bn = blockIdx.x * 64;
    const int ks = blockIdx.z;
    const int tx = tid & 15, ty = tid >> 4;
    const int arow = tid >> 2, akq = tid & 3;
    const int wk = tid >> 4, wnq = tid & 15;

    float acc[4][4] = {};
    const int kbeg = ks * kps, kend = kbeg + kps;

    for (int k0 = kbeg; k0 < kend; k0 += 16) {
        float4 av = *(const float4*)&A[(size_t)(bm + arow) * Kd + k0 + akq * 4];
        float4 wv = *(const float4*)&W[(size_t)(k0 + wk) * N + bn + wnq * 4];
        As[akq * 4 + 0][arow] = av.x;
        As[akq * 4 + 1][arow] = av.y;
        As[akq * 4 + 2][arow] = av.z;
        As[akq * 4 + 3][arow] = av.w;
        *(float4*)&Ws[wk][wnq * 4] = wv;
        __syncthreads();
        #pragma unroll
        for (int kk = 0; kk < 16; ++kk) {
            float4 a4 = *(const float4*)&As[kk][ty * 4];
            float4 b4 = *(const float4*)&Ws[kk][tx * 4];
            float a_[4] = {a4.x, a4.y, a4.z, a4.w};
            float b_[4] = {b4.x, b4.y, b4.z, b4.w};
            #pragma unroll
            for (int i = 0; i < 4; ++i)
                #pragma unroll
                for (int j = 0; j < 4; ++j)
                    acc[i][j] += a_[i] * b_[j];
        }
        __syncthreads();
    }

    float* Pbase = P + (size_t)ks * M * N;
    #pragma unroll
    for (int i = 0; i < 4; ++i) {
        int row = bm + ty * 4 + i;
        float4 v = {acc[i][0], acc[i][1], acc[i][2], acc[i][3]};
        *(float4*)&Pbase[(size_t)row * N + bn + tx * 4] = v;
    }
}

// ---------------------------------------------------------------------------
template<int ACT>
__global__ __launch_bounds__(256)
void reduce_k(const float* __restrict__ P, const float* __restrict__ bias,
              float* __restrict__ C, int MN, int N, int nsplit) {
    int idx = blockIdx.x * 256 + threadIdx.x;
    if (idx >= MN) return;
    float s = 0.f;
    for (int z = 0; z < nsplit; ++z) s += P[(size_t)z * MN + idx];
    if (bias) s += bias[idx & (N - 1)];
    if (ACT == 1) s = fmaxf(s, 0.f);
    C[idx] = s;
}

// ---------------------------------------------------------------------------
// masked softmax over S per batch; input = sum of 8 score slots + b_a2.
__global__ __launch_bounds__(256)
void softmax8(const float* __restrict__ scores8, const float* __restrict__ b_a2,
              const void* __restrict__ masks_raw, const int* __restrict__ flag,
              float* __restrict__ attw) {
    int b = blockIdx.x, tid = threadIdx.x;
    bool isb = (*flag) != 0;
    const unsigned char* mb = (const unsigned char*)masks_raw;
    const int* mi = (const int*)masks_raw;
    int lane = tid & 63, wv = tid >> 6;
    __shared__ float red[4], red2[4];
    float bias = b_a2[0];

    float m = -INFINITY;
    for (int s = tid; s < S_; s += 256) {
        int idx = b * S_ + s;
        float v = bias;
        #pragma unroll
        for (int z = 0; z < 8; ++z) v += scores8[(size_t)z * MS_ + idx];
        bool mk = isb ? (mb[idx] != 0) : (mi[idx] != 0);
        v = mk ? -INFINITY : v;
        attw[idx] = v;
        m = fmaxf(m, v);
    }
    #pragma unroll
    for (int off = 32; off; off >>= 1) m = fmaxf(m, __shfl_down(m, off, 64));
    if (lane == 0) red[wv] = m;
    __syncthreads();
    if (tid == 0) red[0] = fmaxf(fmaxf(red[0], red[1]), fmaxf(red[2], red[3]));
    __syncthreads();
    float Mx = red[0];

    float sum = 0.f;
    for (int s = tid; s < S_; s += 256) {
        int idx = b * S_ + s;
        float e = expf(attw[idx] - Mx);
        attw[idx] = e;
        sum += e;
    }
    #pragma unroll
    for (int off = 32; off; off >>= 1) sum += __shfl_down(sum, off, 64);
    if (lane == 0) red2[wv] = sum;
    __syncthreads();
    if (tid == 0) red2[0] = red2[0] + red2[1] + red2[2] + red2[3];
    __syncthreads();
    float inv = 1.f / red2[0];
    for (int s = tid; s < S_; s += 256) attw[b * S_ + s] *= inv;
}

// ---------------------------------------------------------------------------
// att4[z][b][h] = sum_{s in z-chunk} bf16(mm[b,s,h]) * attw[b,s]
__global__ __launch_bounds__(256)
void attended4(const unsigned short* __restrict__ mm, const float* __restrict__ attw,
               float* __restrict__ att4) {
    int b = blockIdx.x, z = blockIdx.y;
    int h2 = threadIdx.x;                 // h pair index, 256 pairs = 512 h
    __shared__ float w[128];
    int s0 = z * 128;
    if (threadIdx.x < 128) w[threadIdx.x] = attw[b * S_ + s0 + threadIdx.x];
    __syncthreads();
    const unsigned int* base =
        (const unsigned int*)mm + ((size_t)b * S_ + s0) * (HID_ / 2) + h2;
    float a0 = 0.f, a1 = 0.f;
    for (int s = 0; s < 128; ++s) {
        unsigned int u = base[(size_t)s * (HID_ / 2)];
        a0 += __uint_as_float(u << 16) * w[s];
        a1 += __uint_as_float(u & 0xffff0000u) * w[s];
    }
    float2 r = {a0, a1};
    *(float2*)&att4[((size_t)z * B_ + b) * HID_ + h2 * 2] = r;
}

// ---------------------------------------------------------------------------
__global__ __launch_bounds__(256)
void hist_avg(const float* __restrict__ ph, const int* __restrict__ hcnt,
              float* __restrict__ havg) {
    int bk = blockIdx.x;
    int cnt = hcnt[bk];
    float denom = (float)(cnt > 1 ? cnt : 1);
    const float* base = ph + (size_t)bk * HL_ * EMB_;
    for (int e = threadIdx.x; e < EMB_; e += 256) {
        float s = 0.f;
        for (int l = 0; l < cnt; ++l) s += base[l * EMB_ + e];
        havg[bk * EMB_ + e] = s / denom;
    }
}

// ---------------------------------------------------------------------------
// combine_all: reduce split-K partials of hproj(8) and sep0(16), add biases,
// relu/merge per reference, L2-normalize, dot with attended (sum of 4 chunks).
__global__ __launch_bounds__(256)
void combine_all(const float* __restrict__ skA, const float* __restrict__ skB,
                 const float* __restrict__ b_hist, const float* __restrict__ b_sep,
                 const int* __restrict__ hcnt, const float* __restrict__ att4,
                 float* __restrict__ out) {
    const int MNA = B_ * K_ * HID_;
    int bk = blockIdx.x, tid = threadIdx.x;
    int b = bk / K_;
    int cnt = hcnt[bk];
    float sq = 0.f, dt = 0.f;
    #pragma unroll
    for (int i = 0; i < HID_ / 256; ++i) {
        int h = tid + i * 256;
        size_t idx = (size_t)bk * HID_ + h;
        float hp = b_hist[h];
        #pragma unroll
        for (int z = 0; z < 8; ++z) hp += skA[(size_t)z * MNA + idx];
        hp = fmaxf(hp, 0.f);
        float sp = b_sep[h];
        #pragma unroll
        for (int z = 0; z < 16; ++z) sp += skB[(size_t)z * MNA + idx];
        float v = sp + (cnt > 0 ? hp : 0.f);
        v = fmaxf(v, 0.f);
        float at = 0.f;
        #pragma unroll
        for (int z = 0; z < 4; ++z) at += att4[((size_t)z * B_ + b) * HID_ + h];
        sq += v * v;
        dt += v * at;
    }
    #pragma unroll
    for (int off = 32; off; off >>= 1) {
        sq += __shfl_down(sq, off, 64);
        dt += __shfl_down(dt, off, 64);
    }
    __shared__ float rs[4], rd[4];
    int lane = tid & 63, wv = tid >> 6;
    if (lane == 0) { rs[wv] = sq; rd[wv] = dt; }
    __syncthreads();
    if (tid == 0) {
        float Sq = rs[0] + rs[1] + rs[2] + rs[3];
        float Dt = rd[0] + rd[1] + rd[2] + rd[3];
        float norm = fmaxf(sqrtf(Sq), 1e-12f);
        out[bk] = Dt / norm;
    }
}

// ---------------------------------------------------------------------------
extern "C" void kernel_launch(void* const* d_in, const int* in_sizes, int n_in,
                              void* d_out, int out_size, void* d_ws, size_t ws_size,
                              hipStream_t stream) {
    const float* reps     = (const float*)d_in[0];
    const float* sep_imgs = (const float*)d_in[2];
    const float* vctx     = (const float*)d_in[3];
    const float* phist    = (const float*)d_in[4];
    const int*   hcnt     = (const int*)d_in[5];
    const void*  masks    = d_in[6];
    const float* W_sep = (const float*)d_in[7];
    const float* b_sep = (const float*)d_in[8];
    const float* W_e2h = (const float*)d_in[9];
    const float* b_e2h = (const float*)d_in[10];
    const float* W_hist = (const float*)d_in[11];
    const float* b_hist = (const float*)d_in[12];
    const float* W_ctx = (const float*)d_in[13];
    const float* b_ctx = (const float*)d_in[14];
    const float* W_mm = (const float*)d_in[15];
    const float* b_mm = (const float*)d_in[16];
    const float* W_a1 = (const float*)d_in[17];
    const float* b_a1 = (const float*)d_in[18];
    const float* W_a2 = (const float*)d_in[19];
    const float* b_a2 = (const float*)d_in[20];
    float* out = (float*)d_out;

    const size_t MS = (size_t)MS_;
    const int MNA = B_ * K_ * HID_;   // 196608

    // ---- workspace layout ----
    unsigned short* actA  = (unsigned short*)d_ws;          // [MS*HID] input_reps bf16
    unsigned short* actB  = actA + MS * HID_;               // [MS*HID] mm bf16
    unsigned short* WtE2H = actB + MS * HID_;               // [512*768]
    unsigned short* WtMM  = WtE2H + (size_t)EMB_ * HID_;    // [512*512]
    unsigned short* WtA1  = WtMM + (size_t)HID_ * HID_;     // [512*512]
    float* skC    = (float*)(WtA1 + (size_t)HID_ * HID_);   // [64 * 64*512] ctx splits
    float* skA    = skC + (size_t)64 * B_ * HID_;           // [8  * 384*512] hproj splits
    float* skB    = skA + (size_t)8 * MNA;                  // [16 * 384*512] sep0 splits
    float* scores8 = skB + (size_t)16 * MNA;                // [8 * MS]
    float* attw   = scores8 + 8 * MS;                       // [B,S]
    float* att4   = attw + MS;                              // [4,B,HID]
    float* ctx    = att4 + (size_t)4 * B_ * HID_;           // [B,HID]
    float* ctx2   = ctx + B_ * HID_;                        // [B,HID]
    float* havg   = ctx2 + B_ * HID_;                       // [B*K,EMB]
    int*   flag   = (int*)(havg + (size_t)B_ * K_ * EMB_);

    // 1. prep: weight transposes (bf16) + mask dtype probe
    prep<<<dim3(EMB_ / 32, HID_ / 32, 4), 256, 0, stream>>>(
        W_e2h, W_mm, W_a1, WtE2H, WtMM, WtA1, (const unsigned char*)masks, flag);

    // 2. ctx = relu(visual_context @ W_ctx + b_ctx)   [64,512], K=12288, split-K 64
    {
        const int nsp = 64, kps = (K_ * IMG_) / nsp;
        gemm_splitk<<<dim3(8, 1, nsp), 256, 0, stream>>>(vctx, W_ctx, skC,
                                                         B_, HID_, K_ * IMG_, kps);
        reduce_k<1><<<(B_ * HID_ + 255) / 256, 256, 0, stream>>>(skC, b_ctx, ctx,
                                                                 B_ * HID_, HID_, nsp);
    }
    // 3. ctx2 = ctx @ W_mm[H:,:] + b_mm               [64,512], K=512, split-K 8
    {
        const int nsp = 8, kps = HID_ / nsp;
        gemm_splitk<<<dim3(8, 1, nsp), 256, 0, stream>>>(ctx, W_mm + (size_t)HID_ * HID_,
                                                         skC, B_, HID_, HID_, kps);
        reduce_k<0><<<(B_ * HID_ + 255) / 256, 256, 0, stream>>>(skC, b_mm, ctx2,
                                                                 B_ * HID_, HID_, nsp);
    }

    const int big_grid = (MS_ / 256) * (HID_ / 256);   // 256 blocks, % 8 == 0
    // 4. input_reps = relu(reps @ W_e2h + b_e2h)   fp32-in 256-tile MFMA -> actA
    gemm256<true, 1, false><<<big_grid, 512, 0, stream>>>(
        reps, WtE2H, b_e2h, nullptr, 1, actA, nullptr, nullptr, MS_, HID_, EMB_);
    // 5. mm = relu(input_reps @ W_mm[:H] + ctx2[b]) -> bf16 actB
    gemm256<false, 1, false><<<big_grid, 512, 0, stream>>>(
        actA, WtMM, nullptr, ctx2, S_, actB, nullptr, nullptr, MS_, HID_, HID_);
    // 6. fused t=tanh(mm@W_a1+b_a1); scores8 = partial dots with W_a2
    gemm256<false, 0, true><<<big_grid, 512, 0, stream>>>(
        actB, WtA1, b_a1, nullptr, 1, actA, W_a2, scores8, MS_, ATT_, HID_);
    // 7. masked softmax (sums 8 slots + b_a2) -> attw
    softmax8<<<B_, 256, 0, stream>>>(scores8, b_a2, masks, flag, attw);
    // 8. attended partials over 4 s-chunks (vectorized)
    attended4<<<dim3(B_, 4), 256, 0, stream>>>(actB, attw, att4);
    // 9. havg
    hist_avg<<<B_ * K_, 256, 0, stream>>>(phist, hcnt, havg);
    // 10. hproj partials                              [384,512], K=768, split-K 8
    gemm_splitk<<<dim3(8, 6, 8), 256, 0, stream>>>(havg, W_hist, skA,
                                                   B_ * K_, HID_, EMB_, EMB_ / 8);
    // 11. sep0 partials                               [384,512], K=2048, split-K 16
    gemm_splitk<<<dim3(8, 6, 16), 256, 0, stream>>>(sep_imgs, W_sep, skB,
                                                    B_ * K_, HID_, IMG_, IMG_ / 16);
    // 12. combine: reduce partials, relu/merge, L2-normalize, dot -> out [384]
    combine_all<<<B_ * K_, 256, 0, stream>>>(skA, skB, b_hist, b_sep, hcnt,
                                             att4, out);
}